// Round 5
// baseline (105.782 us; speedup 1.0000x reference)
//
#include <hip/hip_runtime.h>

// BahdanauAttention: B=4, LQ=512, LK=512, H=256, all f32.
//   q = query@Wq^T+bq ; k = values@Wk^T+bk
//   scores = sum_h We[h]*tanh(q+k) + be -> softmax over k -> context = attn@values
//
// Algebra:
//   tanh(x) = 1 - 2/(exp(2x)+1); be and sum(We) are additive constants on scores
//   -> softmax-invariant -> dropped. softmax(scores) = softmax(-2t) with
//   t = sum_h We_h/(1+Eq_h*Ek_h), Eq=exp2(SCALE2*q), Ek=exp2(SCALE2*k) precomputed
//   in the projection epilogue (Ek stored transposed [b][h][k]).
//   Quad-rcp: x_i = 1+Eq*Ek_i (i=0..3), P=x0x1x2x3, r=rcp(P);
//   w/x_i = (w*r)*(product of the other three) via prefix products p01,p23 ->
//   14 VALU + 1 trans per 4 elements. Overflow-safe: q+k is ~N(0,0.82^2), so
//   P <= e^{~50} << 3.4e38; all x_i >= 1, no cancellation.
//
// Timing model (r1-r4 reconciliation): dur_us ~= 10us fixed overhead + warm
// kernels; scores/ctx run at ~60% VALUBusy because global staging latency sits
// behind __syncthreads. Fix: T14 reg-prefetch (issue loads during compute of
// the previous chunk, ds_write after the barrier).

#define SCALE2 2.8853900817779268f   // 2*log2(e)

#if defined(__has_builtin)
#if __has_builtin(__builtin_amdgcn_exp2f)
#define FEXP2(x) __builtin_amdgcn_exp2f(x)
#endif
#if __has_builtin(__builtin_amdgcn_rcpf)
#define FRCP(x) __builtin_amdgcn_rcpf(x)
#endif
#endif
#ifndef FEXP2
#define FEXP2(x) exp2f(x)
#endif
#ifndef FRCP
#define FRCP(x) (1.0f/(x))
#endif

// Fused projections. blockIdx.z = 0: Eq[n][o] = exp2(SCALE2*(query@Wq^T+bq))
//                    blockIdx.z = 1: EkT[b][o][k] = exp2(SCALE2*(values@Wk^T+bk))
__global__ __launch_bounds__(512) void proj_kernel(
    const float* __restrict__ Q, const float* __restrict__ V,
    const float* __restrict__ Wq, const float* __restrict__ bq,
    const float* __restrict__ Wk, const float* __restrict__ bk,
    float* __restrict__ Eq, float* __restrict__ EkT)
{
  const int n0 = blockIdx.x * 64;
  const int o0 = blockIdx.y * 64;
  const bool isK = (blockIdx.z == 1);
  const float* X    = isK ? V  : Q;
  const float* W    = isK ? Wk : Wq;
  const float* bias = isK ? bk : bq;
  const int t  = threadIdx.x;
  const int tx = t & 15;        // o quad
  const int ty = t >> 4;        // 0..31 : n pair
  __shared__ float Xst[32][68]; // [h][n]
  __shared__ float Wst[32][68]; // [h][o]
  float acc[2][4] = {};
  const int sr = t >> 3, sc = (t & 7) << 2;   // staging coords: 64 rows x 32 cols
  float4 xv = *(const float4*)(X + (size_t)(n0 + sr) * 256 + sc);
  float4 wv = *(const float4*)(W + (size_t)(o0 + sr) * 256 + sc);
  for (int h0 = 0; h0 < 256; h0 += 32) {
    __syncthreads();
    Xst[sc  ][sr] = xv.x; Xst[sc+1][sr] = xv.y; Xst[sc+2][sr] = xv.z; Xst[sc+3][sr] = xv.w;
    Wst[sc  ][sr] = wv.x; Wst[sc+1][sr] = wv.y; Wst[sc+2][sr] = wv.z; Wst[sc+3][sr] = wv.w;
    __syncthreads();
    if (h0 < 224) {   // prefetch next chunk during compute
      xv = *(const float4*)(X + (size_t)(n0 + sr) * 256 + h0 + 32 + sc);
      wv = *(const float4*)(W + (size_t)(o0 + sr) * 256 + h0 + 32 + sc);
    }
#pragma unroll 8
    for (int hh = 0; hh < 32; ++hh) {
      float2 a  = *(const float2*)&Xst[hh][ty*2];
      float4 bb = *(const float4*)&Wst[hh][tx*4];
      acc[0][0] = fmaf(a.x, bb.x, acc[0][0]); acc[0][1] = fmaf(a.x, bb.y, acc[0][1]);
      acc[0][2] = fmaf(a.x, bb.z, acc[0][2]); acc[0][3] = fmaf(a.x, bb.w, acc[0][3]);
      acc[1][0] = fmaf(a.y, bb.x, acc[1][0]); acc[1][1] = fmaf(a.y, bb.y, acc[1][1]);
      acc[1][2] = fmaf(a.y, bb.z, acc[1][2]); acc[1][3] = fmaf(a.y, bb.w, acc[1][3]);
    }
  }
  const float4 bv = *(const float4*)(bias + o0 + tx*4);
  float e[2][4];
#pragma unroll
  for (int i = 0; i < 2; ++i) {
    e[i][0] = FEXP2(SCALE2 * (acc[i][0] + bv.x));
    e[i][1] = FEXP2(SCALE2 * (acc[i][1] + bv.y));
    e[i][2] = FEXP2(SCALE2 * (acc[i][2] + bv.z));
    e[i][3] = FEXP2(SCALE2 * (acc[i][3] + bv.w));
  }
  if (!isK) {
#pragma unroll
    for (int i = 0; i < 2; ++i) {
      float4 st = {e[i][0], e[i][1], e[i][2], e[i][3]};
      *(float4*)(Eq + (size_t)(n0 + ty*2 + i) * 256 + o0 + tx*4) = st;
    }
  } else {
    const int b  = n0 >> 9;
    const int k0 = (n0 & 511) + ty*2;
#pragma unroll
    for (int j = 0; j < 4; ++j) {
      float2 st = {e[0][j], e[1][j]};
      *(float2*)(EkT + (size_t)b*131072 + (size_t)(o0 + tx*4 + j)*512 + k0) = st;
    }
  }
}

// traw[b][q][k] = sum_h We[h] / (1 + Eq*Ek)   (scores = C - 2*traw)
// tile 16q x 64k, 256 threads, 4 el/thread (quad-rcp). grid (8,32,4) = 1024
// blocks -> 4 blocks/CU x 4 waves. Reg-prefetch double-buffering of staging.
__global__ __launch_bounds__(256) void scores_kernel(
    const float* __restrict__ Eq, const float* __restrict__ EkT,
    const float* __restrict__ We, float* __restrict__ sout)
{
  const int kt = blockIdx.x;      // 0..7
  const int qt = blockIdx.y;      // 0..31
  const int b  = blockIdx.z;      // 0..3
  const int t  = threadIdx.x;
  const int qi = t >> 4;          // 0..15 : q-row
  const int k4 = (t & 15) << 2;   // 0..60 : 4 k-cols

  __shared__ float ks[64][64];    // [h][k]
  __shared__ float qs[16][68];    // padded

  const float* eqbase = Eq  + (size_t)(b*512 + qt*16) * 256;
  const float* ekbase = EkT + (size_t)b*131072 + (size_t)kt*64;

  // staging coords (same every chunk)
  const int er = t >> 4, ec = (t & 15) << 2;        // Eq tile 16x64
  float4 eqv, ekv[4];
  eqv = *(const float4*)(eqbase + (size_t)er*256 + ec);
#pragma unroll
  for (int rep = 0; rep < 4; ++rep) {
    int idx = rep*256 + t;
    int r = idx >> 4, c = (idx & 15) << 2;
    ekv[rep] = *(const float4*)(ekbase + (size_t)r*512 + c);
  }

  float a0 = 0.f, a1 = 0.f, a2 = 0.f, a3 = 0.f;

  for (int h0 = 0; h0 < 256; h0 += 64) {
    __syncthreads();
    *(float4*)&qs[er][ec] = eqv;
#pragma unroll
    for (int rep = 0; rep < 4; ++rep) {
      int idx = rep*256 + t;
      int r = idx >> 4, c = (idx & 15) << 2;
      *(float4*)&ks[r][c] = ekv[rep];
    }
    __syncthreads();
    if (h0 < 192) {   // prefetch next chunk into regs; latency hides under compute
      eqv = *(const float4*)(eqbase + (size_t)er*256 + h0 + 64 + ec);
#pragma unroll
      for (int rep = 0; rep < 4; ++rep) {
        int idx = rep*256 + t;
        int r = idx >> 4, c = (idx & 15) << 2;
        ekv[rep] = *(const float4*)(ekbase + (size_t)(h0 + 64 + r)*512 + c);
      }
    }
#pragma unroll 8
    for (int hh = 0; hh < 64; ++hh) {
      float w  = We[h0 + hh];                      // uniform -> scalar load
      float qv = qs[qi][hh];                       // broadcast
      float4 kv = *(const float4*)&ks[hh][k4];     // b128
      float x0 = fmaf(qv, kv.x, 1.0f);
      float x1 = fmaf(qv, kv.y, 1.0f);
      float x2 = fmaf(qv, kv.z, 1.0f);
      float x3 = fmaf(qv, kv.w, 1.0f);
      float p01 = x0 * x1, p23 = x2 * x3;
      float r4  = FRCP(p01 * p23);                 // one rcp per 4 elements
      float wr  = w * r4;
      float sw  = wr * p23, uw = wr * p01;
      a0 = fmaf(sw, x1, a0);
      a1 = fmaf(sw, x0, a1);
      a2 = fmaf(uw, x3, a2);
      a3 = fmaf(uw, x2, a3);
    }
  }
  float4 st = {a0, a1, a2, a3};
  *(float4*)(sout + (size_t)(b*512 + qt*16 + qi)*512 + kt*64 + k4) = st;
}

// Fused softmax + context. 8 rows/block, 256 blocks, 512 threads.
// Wave w owns row w entirely: softmaxes it, then computes its ctx row.
__global__ __launch_bounds__(512) void ctx_kernel(
    const float* __restrict__ values, float* attn, float* __restrict__ ctx)
{
  const int t    = threadIdx.x;
  const int row0 = blockIdx.x * 8;
  const int b    = row0 >> 9;
  __shared__ float ts[8][512];    // raw t -> normalized attn
  __shared__ float vs[32][256];   // values chunk

  // stage raw scores 8x512 (2 float4/thread)
#pragma unroll
  for (int rep = 0; rep < 2; ++rep) {
    int idx = rep*512 + t;
    int r = idx >> 7, c = (idx & 127) << 2;
    *(float4*)&ts[r][c] = *(const float4*)(attn + (size_t)(row0 + r)*512 + c);
  }
  // prefetch values chunk 0 into regs; completes during softmax
  const float* vbase = values + (size_t)b * 131072;
  float4 pf[4];
#pragma unroll
  for (int rep = 0; rep < 4; ++rep) {
    int idx = rep*512 + t;
    int r = idx >> 6, c = (idx & 63) << 2;
    pf[rep] = *(const float4*)(vbase + (size_t)r*256 + c);
  }
  __syncthreads();

  // softmax(-2t) per row: wave w -> row w; exponent (mn - t)*SCALE2
  const int w = t >> 6, j = t & 63;
  {
    float v[8];
    float mn = 1e30f;
#pragma unroll
    for (int i = 0; i < 8; ++i) { v[i] = ts[w][j + 64*i]; mn = fminf(mn, v[i]); }
#pragma unroll
    for (int off = 32; off > 0; off >>= 1) mn = fminf(mn, __shfl_xor(mn, off, 64));
    float sum = 0.f;
#pragma unroll
    for (int i = 0; i < 8; ++i) { v[i] = FEXP2((mn - v[i]) * SCALE2); sum += v[i]; }
#pragma unroll
    for (int off = 32; off > 0; off >>= 1) sum += __shfl_xor(sum, off, 64);
    const float inv = 1.0f / sum;
    float* gp = attn + (size_t)(row0 + w) * 512 + j;
#pragma unroll
    for (int i = 0; i < 8; ++i) {
      float p = v[i] * inv;
      ts[w][j + 64*i] = p;      // wave-local row: no cross-wave dependency
      gp[64*i] = p;             // coalesced global write of attention output
    }
  }

  // context: thread -> (row w, 4 h-cols). r = w is wave-uniform.
  const int h4 = (t & 63) << 2;
  float4 acc = {0,0,0,0};
  for (int kc = 0; kc < 512; kc += 32) {
    __syncthreads();            // vs free (and ts visible for kc==0)
#pragma unroll
    for (int rep = 0; rep < 4; ++rep) {
      int idx = rep*512 + t;
      int r = idx >> 6, c = (idx & 63) << 2;
      *(float4*)&vs[r][c] = pf[rep];
    }
    __syncthreads();
    if (kc < 480) {             // prefetch next chunk; hides under 32-iter compute
#pragma unroll
      for (int rep = 0; rep < 4; ++rep) {
        int idx = rep*512 + t;
        int r = idx >> 6, c = (idx & 63) << 2;
        pf[rep] = *(const float4*)(vbase + (size_t)(kc + 32 + r)*256 + c);
      }
    }
#pragma unroll 8
    for (int kk = 0; kk < 32; ++kk) {
      float av  = ts[w][kc + kk];                 // wave-uniform broadcast
      float4 vv = *(const float4*)&vs[kk][h4];    // lane-consecutive b128
      acc.x = fmaf(av, vv.x, acc.x);
      acc.y = fmaf(av, vv.y, acc.y);
      acc.z = fmaf(av, vv.z, acc.z);
      acc.w = fmaf(av, vv.w, acc.w);
    }
  }
  *(float4*)(ctx + (size_t)(row0 + w) * 256 + h4) = acc;
}

extern "C" void kernel_launch(void* const* d_in, const int* in_sizes, int n_in,
                              void* d_out, int out_size, void* d_ws, size_t ws_size,
                              hipStream_t stream)
{
  const float* query  = (const float*)d_in[0];
  const float* values = (const float*)d_in[1];
  const float* Wq     = (const float*)d_in[2];
  const float* bq     = (const float*)d_in[3];
  const float* Wk     = (const float*)d_in[4];
  const float* bk     = (const float*)d_in[5];
  const float* We     = (const float*)d_in[6];
  // d_in[7] = be: additive constant on scores -> softmax-invariant -> unused.

  float* ctx  = (float*)d_out;            // 4*512*256 floats
  float* attn = ctx + 4*512*256;          // 4*512*512 floats
  float* Eq   = ctx;                      // alias ctx region; all Eq reads happen
                                          // in scores_kernel, before ctx_kernel
  float* EkT  = (float*)d_ws;             // 2MB of ws, layout [b][h][k]

  proj_kernel  <<<dim3(32, 4, 2), 512, 0, stream>>>(query, values, Wq, bq, Wk, bk, Eq, EkT);
  scores_kernel<<<dim3(8, 32, 4), 256, 0, stream>>>(Eq, EkT, We, attn);
  ctx_kernel   <<<256, 512, 0, stream>>>(values, attn, ctx);
}

// Round 6
// 69.638 us; speedup vs baseline: 1.5190x; 1.5190x over previous
//
#include <hip/hip_runtime.h>

// BahdanauAttention: B=4, LQ=512, LK=512, H=256, all f32.
//   q = query@Wq^T+bq ; k = values@Wk^T+bk
//   scores = sum_h We[h]*tanh(q+k) + be -> softmax over k -> context = attn@values
//
// Algebra:
//   tanh(x) = 1 - 2/(exp(2x)+1); be and sum(We) are additive constants on scores
//   -> softmax-invariant -> dropped. softmax(scores) = softmax(-2t) with
//   t = sum_h We_h/(1+Eq_h*Ek_h), Eq=exp2(SCALE2*q), Ek=exp2(SCALE2*k) precomputed
//   in the projection epilogue (Ek stored transposed [b][h][k]).
//   Quad-rcp: x_i = 1+Eq*Ek_i, P=x0x1x2x3, r=rcp(P); w/x_i via prefix products ->
//   14 VALU + 1 trans per 4 elements. Overflow-safe (P <= e^~50), x_i >= 1.
//
// r5 decomposition: scores 49us (occupancy-starved at 1024 blocks), ctx 48us
// (1 block/CU + 1GB LDS-read floor from re-reading values once per row).
// This round: scores h-split partials (grid 2048, p0+p1 summed in ctx staging);
// ctx restructured to rows-in-registers k-split (values element read once per
// block, 8x less LDS traffic) + cross-wave LDS reduction.

#define SCALE2 2.8853900817779268f   // 2*log2(e)

#if defined(__has_builtin)
#if __has_builtin(__builtin_amdgcn_exp2f)
#define FEXP2(x) __builtin_amdgcn_exp2f(x)
#endif
#if __has_builtin(__builtin_amdgcn_rcpf)
#define FRCP(x) __builtin_amdgcn_rcpf(x)
#endif
#endif
#ifndef FEXP2
#define FEXP2(x) exp2f(x)
#endif
#ifndef FRCP
#define FRCP(x) (1.0f/(x))
#endif

// Fused projections. blockIdx.z = 0: Eq[n][o] = exp2(SCALE2*(query@Wq^T+bq))
//                    blockIdx.z = 1: EkT[b][o][k] = exp2(SCALE2*(values@Wk^T+bk))
__global__ __launch_bounds__(512) void proj_kernel(
    const float* __restrict__ Q, const float* __restrict__ V,
    const float* __restrict__ Wq, const float* __restrict__ bq,
    const float* __restrict__ Wk, const float* __restrict__ bk,
    float* __restrict__ Eq, float* __restrict__ EkT)
{
  const int n0 = blockIdx.x * 64;
  const int o0 = blockIdx.y * 64;
  const bool isK = (blockIdx.z == 1);
  const float* X    = isK ? V  : Q;
  const float* W    = isK ? Wk : Wq;
  const float* bias = isK ? bk : bq;
  const int t  = threadIdx.x;
  const int tx = t & 15;        // o quad
  const int ty = t >> 4;        // 0..31 : n pair
  __shared__ float Xst[32][68]; // [h][n]
  __shared__ float Wst[32][68]; // [h][o]
  float acc[2][4] = {};
  const int sr = t >> 3, sc = (t & 7) << 2;   // staging coords: 64 rows x 32 cols
  float4 xv = *(const float4*)(X + (size_t)(n0 + sr) * 256 + sc);
  float4 wv = *(const float4*)(W + (size_t)(o0 + sr) * 256 + sc);
  for (int h0 = 0; h0 < 256; h0 += 32) {
    __syncthreads();
    Xst[sc  ][sr] = xv.x; Xst[sc+1][sr] = xv.y; Xst[sc+2][sr] = xv.z; Xst[sc+3][sr] = xv.w;
    Wst[sc  ][sr] = wv.x; Wst[sc+1][sr] = wv.y; Wst[sc+2][sr] = wv.z; Wst[sc+3][sr] = wv.w;
    __syncthreads();
    if (h0 < 224) {   // prefetch next chunk during compute
      xv = *(const float4*)(X + (size_t)(n0 + sr) * 256 + h0 + 32 + sc);
      wv = *(const float4*)(W + (size_t)(o0 + sr) * 256 + h0 + 32 + sc);
    }
#pragma unroll 8
    for (int hh = 0; hh < 32; ++hh) {
      float2 a  = *(const float2*)&Xst[hh][ty*2];
      float4 bb = *(const float4*)&Wst[hh][tx*4];
      acc[0][0] = fmaf(a.x, bb.x, acc[0][0]); acc[0][1] = fmaf(a.x, bb.y, acc[0][1]);
      acc[0][2] = fmaf(a.x, bb.z, acc[0][2]); acc[0][3] = fmaf(a.x, bb.w, acc[0][3]);
      acc[1][0] = fmaf(a.y, bb.x, acc[1][0]); acc[1][1] = fmaf(a.y, bb.y, acc[1][1]);
      acc[1][2] = fmaf(a.y, bb.z, acc[1][2]); acc[1][3] = fmaf(a.y, bb.w, acc[1][3]);
    }
  }
  const float4 bv = *(const float4*)(bias + o0 + tx*4);
  float e[2][4];
#pragma unroll
  for (int i = 0; i < 2; ++i) {
    e[i][0] = FEXP2(SCALE2 * (acc[i][0] + bv.x));
    e[i][1] = FEXP2(SCALE2 * (acc[i][1] + bv.y));
    e[i][2] = FEXP2(SCALE2 * (acc[i][2] + bv.z));
    e[i][3] = FEXP2(SCALE2 * (acc[i][3] + bv.w));
  }
  if (!isK) {
#pragma unroll
    for (int i = 0; i < 2; ++i) {
      float4 st = {e[i][0], e[i][1], e[i][2], e[i][3]};
      *(float4*)(Eq + (size_t)(n0 + ty*2 + i) * 256 + o0 + tx*4) = st;
    }
  } else {
    const int b  = n0 >> 9;
    const int k0 = (n0 & 511) + ty*2;
#pragma unroll
    for (int j = 0; j < 4; ++j) {
      float2 st = {e[0][j], e[1][j]};
      *(float2*)(EkT + (size_t)b*131072 + (size_t)(o0 + tx*4 + j)*512 + k0) = st;
    }
  }
}

// Partial t over an h-half: p[b][q][k] = sum_{h in half} We[h]/(1+Eq*Ek).
// tile 16q x 64k, 256 threads, 4 el/thread (quad-rcp). grid (16,32,4) = 2048
// blocks (x = kt + 8*half) -> 8 blocks/CU, ~28 waves/CU.
__global__ __launch_bounds__(256) void scores_kernel(
    const float* __restrict__ Eq, const float* __restrict__ EkT,
    const float* __restrict__ We, float* __restrict__ p0, float* __restrict__ p1)
{
  const int kt   = blockIdx.x & 7;     // 0..7
  const int half = blockIdx.x >> 3;    // 0..1
  const int qt = blockIdx.y;           // 0..31
  const int b  = blockIdx.z;           // 0..3
  const int t  = threadIdx.x;
  const int qi = t >> 4;               // 0..15 : q-row
  const int k4 = (t & 15) << 2;        // 0..60 : 4 k-cols

  __shared__ float ks[64][64];         // [h][k]
  __shared__ float qs[16][68];         // padded

  const int hbase = half * 128;
  const float* eqbase = Eq  + (size_t)(b*512 + qt*16) * 256 + hbase;
  const float* ekbase = EkT + (size_t)b*131072 + (size_t)hbase*512 + (size_t)kt*64;
  const float* Weh    = We + hbase;
  float* sout = half ? p1 : p0;

  const int er = t >> 4, ec = (t & 15) << 2;   // Eq tile 16x64 staging coords
  float4 eqv, ekv[4];
  eqv = *(const float4*)(eqbase + (size_t)er*256 + ec);
#pragma unroll
  for (int rep = 0; rep < 4; ++rep) {
    int idx = rep*256 + t;
    int r = idx >> 4, c = (idx & 15) << 2;
    ekv[rep] = *(const float4*)(ekbase + (size_t)r*512 + c);
  }

  float a0 = 0.f, a1 = 0.f, a2 = 0.f, a3 = 0.f;

  for (int h0 = 0; h0 < 128; h0 += 64) {
    __syncthreads();
    *(float4*)&qs[er][ec] = eqv;
#pragma unroll
    for (int rep = 0; rep < 4; ++rep) {
      int idx = rep*256 + t;
      int r = idx >> 4, c = (idx & 15) << 2;
      *(float4*)&ks[r][c] = ekv[rep];
    }
    __syncthreads();
    if (h0 == 0) {   // prefetch second chunk into regs; hides under compute
      eqv = *(const float4*)(eqbase + (size_t)er*256 + 64 + ec);
#pragma unroll
      for (int rep = 0; rep < 4; ++rep) {
        int idx = rep*256 + t;
        int r = idx >> 4, c = (idx & 15) << 2;
        ekv[rep] = *(const float4*)(ekbase + (size_t)(64 + r)*512 + c);
      }
    }
#pragma unroll 8
    for (int hh = 0; hh < 64; ++hh) {
      float w  = Weh[h0 + hh];                     // uniform -> scalar load
      float qv = qs[qi][hh];                       // broadcast
      float4 kv = *(const float4*)&ks[hh][k4];     // b128
      float x0 = fmaf(qv, kv.x, 1.0f);
      float x1 = fmaf(qv, kv.y, 1.0f);
      float x2 = fmaf(qv, kv.z, 1.0f);
      float x3 = fmaf(qv, kv.w, 1.0f);
      float p01 = x0 * x1, p23 = x2 * x3;
      float r4  = FRCP(p01 * p23);                 // one rcp per 4 elements
      float wr  = w * r4;
      float sw  = wr * p23, uw = wr * p01;
      a0 = fmaf(sw, x1, a0);
      a1 = fmaf(sw, x0, a1);
      a2 = fmaf(uw, x3, a2);
      a3 = fmaf(uw, x2, a3);
    }
  }
  float4 st = {a0, a1, a2, a3};
  *(float4*)(sout + (size_t)(b*512 + qt*16 + qi)*512 + kt*64 + k4) = st;
}

// Fused softmax + context. 8 rows/block, 256 blocks, 512 threads.
// Stage ts = p0+p1; wave w softmaxes row w (writes attn out); then each wave
// takes k-slice [w*64,(w+1)*64): acc[8] row-accumulators in registers, values
// read once per block straight from global (b128, L2-resident), attn via
// uniform b128 LDS broadcasts; cross-wave reduction through red[][][] in LDS.
__global__ __launch_bounds__(512) void ctx_kernel(
    const float* __restrict__ values, const float* __restrict__ p0,
    const float* __restrict__ p1, float* __restrict__ attn,
    float* __restrict__ ctx)
{
  const int t    = threadIdx.x;
  const int row0 = blockIdx.x * 8;
  const int b    = row0 >> 9;
  __shared__ float ts[8][512];        // 16KB: t partials -> normalized attn
  __shared__ float red[8][8][256];    // 64KB: per-wave partial ctx

  // stage ts = p0 + p1 (8 rows x 512)
#pragma unroll
  for (int rep = 0; rep < 2; ++rep) {
    int idx = rep*512 + t;
    int r = idx >> 7, c = (idx & 127) << 2;
    size_t off = (size_t)(row0 + r)*512 + c;
    float4 v0 = *(const float4*)(p0 + off);
    float4 v1 = *(const float4*)(p1 + off);
    float4 s = {v0.x+v1.x, v0.y+v1.y, v0.z+v1.z, v0.w+v1.w};
    *(float4*)&ts[r][c] = s;
  }
  __syncthreads();

  const int w = t >> 6, j = t & 63;   // wave id, lane
  // softmax(-2t): wave w -> row w; exponent (mn - t)*SCALE2
  {
    float v[8];
    float mn = 1e30f;
#pragma unroll
    for (int i = 0; i < 8; ++i) { v[i] = ts[w][j + 64*i]; mn = fminf(mn, v[i]); }
#pragma unroll
    for (int off = 32; off > 0; off >>= 1) mn = fminf(mn, __shfl_xor(mn, off, 64));
    float sum = 0.f;
#pragma unroll
    for (int i = 0; i < 8; ++i) { v[i] = FEXP2((mn - v[i]) * SCALE2); sum += v[i]; }
#pragma unroll
    for (int off = 32; off > 0; off >>= 1) sum += __shfl_xor(sum, off, 64);
    const float inv = 1.0f / sum;
    float* gp = attn + (size_t)(row0 + w) * 512 + j;
#pragma unroll
    for (int i = 0; i < 8; ++i) {
      float p = v[i] * inv;
      ts[w][j + 64*i] = p;      // wave-local row: no cross-wave dependency yet
      gp[64*i] = p;             // coalesced attention output
    }
  }
  __syncthreads();              // all rows of ts normalized

  // context partials: wave w -> k in [w*64, w*64+64), lane -> 4 h-cols
  const int h4 = j << 2;
  const int wk0 = w * 64;
  const float* vwb = values + (size_t)b*131072 + (size_t)wk0*256 + h4;
  float4 acc[8];
#pragma unroll
  for (int r = 0; r < 8; ++r) acc[r] = (float4){0,0,0,0};

  float4 cv[4], nv[4];
#pragma unroll
  for (int jj = 0; jj < 4; ++jj) cv[jj] = *(const float4*)(vwb + (size_t)jj*256);

  for (int kq = 0; kq < 16; ++kq) {        // 16 quads of k
    if (kq < 15) {
#pragma unroll
      for (int jj = 0; jj < 4; ++jj)
        nv[jj] = *(const float4*)(vwb + (size_t)((kq+1)*4 + jj)*256);
    }
    float4 a[8];
#pragma unroll
    for (int r = 0; r < 8; ++r) a[r] = *(const float4*)&ts[r][wk0 + kq*4]; // b128 bcast
#pragma unroll
    for (int jj = 0; jj < 4; ++jj) {
      float4 v4 = cv[jj];
#pragma unroll
      for (int r = 0; r < 8; ++r) {
        float ar = (jj == 0) ? a[r].x : (jj == 1) ? a[r].y : (jj == 2) ? a[r].z : a[r].w;
        acc[r].x = fmaf(ar, v4.x, acc[r].x);
        acc[r].y = fmaf(ar, v4.y, acc[r].y);
        acc[r].z = fmaf(ar, v4.z, acc[r].z);
        acc[r].w = fmaf(ar, v4.w, acc[r].w);
      }
    }
#pragma unroll
    for (int jj = 0; jj < 4; ++jj) cv[jj] = nv[jj];
  }

  // write per-wave partials, reduce across waves
#pragma unroll
  for (int r = 0; r < 8; ++r) *(float4*)&red[w][r][h4] = acc[r];
  __syncthreads();
  {
    const int rr = t >> 6;               // row 0..7 (wave-uniform)
    const int hh4 = (t & 63) << 2;
    float4 s = *(const float4*)&red[0][rr][hh4];
#pragma unroll
    for (int ww = 1; ww < 8; ++ww) {
      float4 p = *(const float4*)&red[ww][rr][hh4];
      s.x += p.x; s.y += p.y; s.z += p.z; s.w += p.w;
    }
    *(float4*)(ctx + (size_t)(row0 + rr)*256 + hh4) = s;
  }
}

extern "C" void kernel_launch(void* const* d_in, const int* in_sizes, int n_in,
                              void* d_out, int out_size, void* d_ws, size_t ws_size,
                              hipStream_t stream)
{
  const float* query  = (const float*)d_in[0];
  const float* values = (const float*)d_in[1];
  const float* Wq     = (const float*)d_in[2];
  const float* bq     = (const float*)d_in[3];
  const float* Wk     = (const float*)d_in[4];
  const float* bk     = (const float*)d_in[5];
  const float* We     = (const float*)d_in[6];
  // d_in[7] = be: additive constant on scores -> softmax-invariant -> unused.

  float* ctx  = (float*)d_out;            // 4*512*256 floats
  float* attn = ctx + 4*512*256;          // 4*512*512 floats (final attention)
  float* Eq   = ctx;                      // alias ctx region; all Eq reads happen
                                          // in scores_kernel, before ctx_kernel
  float* EkT  = (float*)d_ws;             // [b][h][k], 524288 floats
  float* pt0  = EkT + 524288;             // partial t, h-half 0 (4MB)
  float* pt1  = pt0 + 1048576;            // partial t, h-half 1 (4MB)

  proj_kernel  <<<dim3(32, 4, 2), 512, 0, stream>>>(query, values, Wq, bq, Wk, bk, Eq, EkT);
  scores_kernel<<<dim3(16, 32, 4), 256, 0, stream>>>(Eq, EkT, We, pt0, pt1);
  ctx_kernel   <<<256, 512, 0, stream>>>(values, pt0, pt1, attn, ctx);
}

// Round 7
// 65.001 us; speedup vs baseline: 1.6274x; 1.0713x over previous
//
#include <hip/hip_runtime.h>

// BahdanauAttention: B=4, LQ=512, LK=512, H=256, all f32.
//   q = query@Wq^T+bq ; k = values@Wk^T+bk
//   scores = sum_h We[h]*tanh(q+k) + be -> softmax over k -> context = attn@values
//
// Algebra:
//   tanh(x) = 1 - 2/(exp(2x)+1); be and sum(We) are additive constants on scores
//   -> softmax-invariant -> dropped. softmax(scores) = softmax(-2t) with
//   t = sum_h We_h/(1+Eq_h*Ek_h), Eq=exp2(SCALE2*q), Ek=exp2(SCALE2*k), both
//   precomputed TRANSPOSED [b][h][n] in the projection epilogue.
//   Quad-rcp: x_i = 1+Eq*Ek_i, P=x0x1x2x3, r=rcp(P); w/x_i via prefix products ->
//   14 VALU + 1 trans per 4 elements. Overflow-safe (P <= e^~80 tail), x_i >= 1.
//
// r6 post-mortem: scores was LDS-read-pipe bound (2 ds_reads per 4 elements;
// 71 cy LDS vs 36 cy VALU per CU-round -> VALUBusy 58%). Fix: 4q x 4k register
// blocking -> 2 ds_read_b128 per 16 elements; VALU becomes the binding pipe.
// Both operands transposed so staging is contiguous b128, conflict-free, no pads.
// XCD-grouped block decode: all 64 (qt,kt) blocks of one (b,half) land on one
// XCD (xcd = flat&7) -> operand panels fetched into a single L2.

#define SCALE2 2.8853900817779268f   // 2*log2(e)

#if defined(__has_builtin)
#if __has_builtin(__builtin_amdgcn_exp2f)
#define FEXP2(x) __builtin_amdgcn_exp2f(x)
#endif
#if __has_builtin(__builtin_amdgcn_rcpf)
#define FRCP(x) __builtin_amdgcn_rcpf(x)
#endif
#endif
#ifndef FEXP2
#define FEXP2(x) exp2f(x)
#endif
#ifndef FRCP
#define FRCP(x) (1.0f/(x))
#endif

// Fused projections. blockIdx.z = 0: EqT[b][o][q] = exp2(SCALE2*(query@Wq^T+bq))
//                    blockIdx.z = 1: EkT[b][o][k] = exp2(SCALE2*(values@Wk^T+bk))
__global__ __launch_bounds__(512) void proj_kernel(
    const float* __restrict__ Q, const float* __restrict__ V,
    const float* __restrict__ Wq, const float* __restrict__ bq,
    const float* __restrict__ Wk, const float* __restrict__ bk,
    float* __restrict__ EqT, float* __restrict__ EkT)
{
  const int n0 = blockIdx.x * 64;
  const int o0 = blockIdx.y * 64;
  const bool isK = (blockIdx.z == 1);
  const float* X    = isK ? V  : Q;
  const float* W    = isK ? Wk : Wq;
  const float* bias = isK ? bk : bq;
  const int t  = threadIdx.x;
  const int tx = t & 15;        // o quad
  const int ty = t >> 4;        // 0..31 : n pair
  __shared__ float Xst[32][68]; // [h][n]
  __shared__ float Wst[32][68]; // [h][o]
  float acc[2][4] = {};
  const int sr = t >> 3, sc = (t & 7) << 2;   // staging coords: 64 rows x 32 cols
  float4 xv = *(const float4*)(X + (size_t)(n0 + sr) * 256 + sc);
  float4 wv = *(const float4*)(W + (size_t)(o0 + sr) * 256 + sc);
  for (int h0 = 0; h0 < 256; h0 += 32) {
    __syncthreads();
    Xst[sc  ][sr] = xv.x; Xst[sc+1][sr] = xv.y; Xst[sc+2][sr] = xv.z; Xst[sc+3][sr] = xv.w;
    Wst[sc  ][sr] = wv.x; Wst[sc+1][sr] = wv.y; Wst[sc+2][sr] = wv.z; Wst[sc+3][sr] = wv.w;
    __syncthreads();
    if (h0 < 224) {   // prefetch next chunk during compute
      xv = *(const float4*)(X + (size_t)(n0 + sr) * 256 + h0 + 32 + sc);
      wv = *(const float4*)(W + (size_t)(o0 + sr) * 256 + h0 + 32 + sc);
    }
#pragma unroll 8
    for (int hh = 0; hh < 32; ++hh) {
      float2 a  = *(const float2*)&Xst[hh][ty*2];
      float4 bb = *(const float4*)&Wst[hh][tx*4];
      acc[0][0] = fmaf(a.x, bb.x, acc[0][0]); acc[0][1] = fmaf(a.x, bb.y, acc[0][1]);
      acc[0][2] = fmaf(a.x, bb.z, acc[0][2]); acc[0][3] = fmaf(a.x, bb.w, acc[0][3]);
      acc[1][0] = fmaf(a.y, bb.x, acc[1][0]); acc[1][1] = fmaf(a.y, bb.y, acc[1][1]);
      acc[1][2] = fmaf(a.y, bb.z, acc[1][2]); acc[1][3] = fmaf(a.y, bb.w, acc[1][3]);
    }
  }
  const float4 bv = *(const float4*)(bias + o0 + tx*4);
  float e[2][4];
#pragma unroll
  for (int i = 0; i < 2; ++i) {
    e[i][0] = FEXP2(SCALE2 * (acc[i][0] + bv.x));
    e[i][1] = FEXP2(SCALE2 * (acc[i][1] + bv.y));
    e[i][2] = FEXP2(SCALE2 * (acc[i][2] + bv.z));
    e[i][3] = FEXP2(SCALE2 * (acc[i][3] + bv.w));
  }
  // transposed store for BOTH operands: outT[b][o][n]
  float* outT = isK ? EkT : EqT;
  const int b  = n0 >> 9;
  const int nl = (n0 & 511) + ty*2;
#pragma unroll
  for (int j = 0; j < 4; ++j) {
    float2 st = {e[0][j], e[1][j]};
    *(float2*)(outT + (size_t)b*131072 + (size_t)(o0 + tx*4 + j)*512 + nl) = st;
  }
}

// Partial t over a 64-h slice: pt[half][b][q][k] = sum_h We/(1+Eq*Ek).
// tile 64q x 64k x 64h, 256 threads, thread = 4q x 4k (quad-rcp per q-row).
// grid 1024 flat; decode groups all 64 (qt,kt) blocks of one (b,half) onto one
// XCD (xcd = flat&7, 2 z-groups per XCD).
__global__ __launch_bounds__(256) void scores_kernel(
    const float* __restrict__ EqT, const float* __restrict__ EkT,
    const float* __restrict__ We, float* __restrict__ pt)
{
  const int flat = blockIdx.x;
  const int u = flat & 7, v = flat >> 3;
  const int z  = u*2 + (v >> 6);     // 0..15 : (b,half), XCD-resident
  const int qt = (v >> 3) & 7;       // 0..7
  const int kt = v & 7;              // 0..7
  const int b = z >> 2, half = z & 3;
  const int h0 = half * 64;
  const int t  = threadIdx.x;
  const int qr = t >> 4;             // 0..15 : q quad index
  const int kr = t & 15;             // 0..15 : k quad index

  __shared__ float qsT[64][64];      // [h][q]
  __shared__ float ks [64][64];      // [h][k]

  const float* eqb = EqT + (size_t)b*131072 + (size_t)h0*512 + qt*64;
  const float* ekb = EkT + (size_t)b*131072 + (size_t)h0*512 + kt*64;

  // stage both 64h x 64n panels: contiguous b128 writes, conflict-free
#pragma unroll
  for (int rep = 0; rep < 4; ++rep) {
    int idx = rep*256 + t;
    int r = idx >> 4, c = (idx & 15) << 2;
    *(float4*)&qsT[r][c] = *(const float4*)(eqb + (size_t)r*512 + c);
    *(float4*)&ks [r][c] = *(const float4*)(ekb + (size_t)r*512 + c);
  }
  __syncthreads();

  float a[4][4];
#pragma unroll
  for (int i = 0; i < 4; ++i)
#pragma unroll
    for (int j = 0; j < 4; ++j) a[i][j] = 0.f;

#pragma unroll 4
  for (int hh = 0; hh < 64; ++hh) {
    const float w = We[h0 + hh];                       // uniform -> scalar load
    const float4 qv = *(const float4*)&qsT[hh][qr*4];  // b128 broadcast (16 lanes/chunk)
    const float4 kv = *(const float4*)&ks [hh][kr*4];  // b128 broadcast (4 lanes/chunk)
    const float qa[4] = {qv.x, qv.y, qv.z, qv.w};
#pragma unroll
    for (int i = 0; i < 4; ++i) {
      float x0 = fmaf(qa[i], kv.x, 1.0f);
      float x1 = fmaf(qa[i], kv.y, 1.0f);
      float x2 = fmaf(qa[i], kv.z, 1.0f);
      float x3 = fmaf(qa[i], kv.w, 1.0f);
      float p01 = x0 * x1, p23 = x2 * x3;
      float r4  = FRCP(p01 * p23);                     // one rcp per 4 elements
      float wr  = w * r4;
      float sw  = wr * p23, uw = wr * p01;
      a[i][0] = fmaf(sw, x1, a[i][0]);
      a[i][1] = fmaf(sw, x0, a[i][1]);
      a[i][2] = fmaf(uw, x3, a[i][2]);
      a[i][3] = fmaf(uw, x2, a[i][3]);
    }
  }

  float* sout = pt + (size_t)half*1048576
                   + (size_t)(b*512 + qt*64 + qr*4)*512 + kt*64 + kr*4;
#pragma unroll
  for (int i = 0; i < 4; ++i) {
    float4 st = {a[i][0], a[i][1], a[i][2], a[i][3]};
    *(float4*)(sout + (size_t)i*512) = st;
  }
}

// Fused softmax + context. 8 rows/block, 256 blocks, 512 threads.
// Stage ts = sum of 4 h-partials; wave w softmaxes row w (writes attn out);
// then wave w takes k-slice [w*64,(w+1)*64): acc[8] row-accumulators in
// registers, values read once per block straight from global (b128, L2-hot),
// attn via uniform b128 LDS broadcasts; cross-wave reduction through red[].
__global__ __launch_bounds__(512) void ctx_kernel(
    const float* __restrict__ values, const float* __restrict__ pt,
    float* __restrict__ attn, float* __restrict__ ctx)
{
  const int t    = threadIdx.x;
  const int row0 = blockIdx.x * 8;
  const int b    = row0 >> 9;
  __shared__ float ts[8][512];        // 16KB: summed t -> normalized attn
  __shared__ float red[8][8][256];    // 64KB: per-wave partial ctx

  // stage ts = pt0+pt1+pt2+pt3 (8 rows x 512)
#pragma unroll
  for (int rep = 0; rep < 2; ++rep) {
    int idx = rep*512 + t;
    int r = idx >> 7, c = (idx & 127) << 2;
    size_t off = (size_t)(row0 + r)*512 + c;
    float4 v0 = *(const float4*)(pt + off);
    float4 v1 = *(const float4*)(pt + 1048576 + off);
    float4 v2 = *(const float4*)(pt + 2097152 + off);
    float4 v3 = *(const float4*)(pt + 3145728 + off);
    float4 s = {v0.x+v1.x+v2.x+v3.x, v0.y+v1.y+v2.y+v3.y,
                v0.z+v1.z+v2.z+v3.z, v0.w+v1.w+v2.w+v3.w};
    *(float4*)&ts[r][c] = s;
  }
  __syncthreads();

  const int w = t >> 6, j = t & 63;   // wave id, lane
  // softmax(-2t): wave w -> row w; exponent (mn - t)*SCALE2
  {
    float v[8];
    float mn = 1e30f;
#pragma unroll
    for (int i = 0; i < 8; ++i) { v[i] = ts[w][j + 64*i]; mn = fminf(mn, v[i]); }
#pragma unroll
    for (int off = 32; off > 0; off >>= 1) mn = fminf(mn, __shfl_xor(mn, off, 64));
    float sum = 0.f;
#pragma unroll
    for (int i = 0; i < 8; ++i) { v[i] = FEXP2((mn - v[i]) * SCALE2); sum += v[i]; }
#pragma unroll
    for (int off = 32; off > 0; off >>= 1) sum += __shfl_xor(sum, off, 64);
    const float inv = 1.0f / sum;
    float* gp = attn + (size_t)(row0 + w) * 512 + j;
#pragma unroll
    for (int i = 0; i < 8; ++i) {
      float p = v[i] * inv;
      ts[w][j + 64*i] = p;      // wave-local row: no cross-wave dependency yet
      gp[64*i] = p;             // coalesced attention output
    }
  }
  __syncthreads();              // all rows of ts normalized

  // context partials: wave w -> k in [w*64, w*64+64), lane -> 4 h-cols
  const int h4 = j << 2;
  const int wk0 = w * 64;
  const float* vwb = values + (size_t)b*131072 + (size_t)wk0*256 + h4;
  float4 acc[8];
#pragma unroll
  for (int r = 0; r < 8; ++r) acc[r] = (float4){0,0,0,0};

  float4 cv[4], nv[4];
#pragma unroll
  for (int jj = 0; jj < 4; ++jj) cv[jj] = *(const float4*)(vwb + (size_t)jj*256);

  for (int kq = 0; kq < 16; ++kq) {        // 16 quads of k
    if (kq < 15) {
#pragma unroll
      for (int jj = 0; jj < 4; ++jj)
        nv[jj] = *(const float4*)(vwb + (size_t)((kq+1)*4 + jj)*256);
    }
    float4 a[8];
#pragma unroll
    for (int r = 0; r < 8; ++r) a[r] = *(const float4*)&ts[r][wk0 + kq*4]; // b128 bcast
#pragma unroll
    for (int jj = 0; jj < 4; ++jj) {
      float4 v4 = cv[jj];
#pragma unroll
      for (int r = 0; r < 8; ++r) {
        float ar = (jj == 0) ? a[r].x : (jj == 1) ? a[r].y : (jj == 2) ? a[r].z : a[r].w;
        acc[r].x = fmaf(ar, v4.x, acc[r].x);
        acc[r].y = fmaf(ar, v4.y, acc[r].y);
        acc[r].z = fmaf(ar, v4.z, acc[r].z);
        acc[r].w = fmaf(ar, v4.w, acc[r].w);
      }
    }
#pragma unroll
    for (int jj = 0; jj < 4; ++jj) cv[jj] = nv[jj];
  }

  // write per-wave partials, reduce across waves
#pragma unroll
  for (int r = 0; r < 8; ++r) *(float4*)&red[w][r][h4] = acc[r];
  __syncthreads();
  {
    const int rr = t >> 6;               // row 0..7 (wave-uniform)
    const int hh4 = (t & 63) << 2;
    float4 s = *(const float4*)&red[0][rr][hh4];
#pragma unroll
    for (int ww = 1; ww < 8; ++ww) {
      float4 p = *(const float4*)&red[ww][rr][hh4];
      s.x += p.x; s.y += p.y; s.z += p.z; s.w += p.w;
    }
    *(float4*)(ctx + (size_t)(row0 + rr)*256 + hh4) = s;
  }
}

extern "C" void kernel_launch(void* const* d_in, const int* in_sizes, int n_in,
                              void* d_out, int out_size, void* d_ws, size_t ws_size,
                              hipStream_t stream)
{
  const float* query  = (const float*)d_in[0];
  const float* values = (const float*)d_in[1];
  const float* Wq     = (const float*)d_in[2];
  const float* bq     = (const float*)d_in[3];
  const float* Wk     = (const float*)d_in[4];
  const float* bk     = (const float*)d_in[5];
  const float* We     = (const float*)d_in[6];
  // d_in[7] = be: additive constant on scores -> softmax-invariant -> unused.

  float* ctx  = (float*)d_out;            // 4*512*256 floats
  float* attn = ctx + 4*512*256;          // 4*512*512 floats (final attention)
  float* EqT  = (float*)d_ws;             // [b][h][q], 524288 floats (2MB)
  float* EkT  = EqT + 524288;             // [b][h][k], 524288 floats (2MB)
  float* pt   = EkT + 524288;             // 4 h-partials, 4x 1048576 floats (16MB)

  proj_kernel  <<<dim3(32, 4, 2), 512, 0, stream>>>(query, values, Wq, bq, Wk, bk, EqT, EkT);
  scores_kernel<<<1024, 256, 0, stream>>>(EqT, EkT, We, pt);
  ctx_kernel   <<<256, 512, 0, stream>>>(values, pt, attn, ctx);
}